// Round 1
// baseline (179.888 us; speedup 1.0000x reference)
//
#include <hip/hip_runtime.h>
#include <hip/hip_bf16.h>

typedef unsigned int  uint;
typedef unsigned short ushort;
typedef short bf16x8 __attribute__((ext_vector_type(8)));
typedef float f32x4  __attribute__((ext_vector_type(4)));

#define HW   4096
#define KD   2304   // 9 taps * 256 c

__device__ __forceinline__ void load_lds16(const void* g, void* l) {
    __builtin_amdgcn_global_load_lds((const __attribute__((address_space(1))) void*)g,
                                     (__attribute__((address_space(3))) void*)l, 16, 0, 0);
}
__device__ __forceinline__ float blo(uint u) { return __uint_as_float(u << 16); }
__device__ __forceinline__ float bhi(uint u) { return __uint_as_float(u & 0xffff0000u); }
__device__ __forceinline__ uint pack2(float e, float o) {
    __hip_bfloat16 he = __float2bfloat16(e), ho = __float2bfloat16(o);
    return (uint)(*(ushort*)&he) | ((uint)(*(ushort*)&ho) << 16);
}

// ---- x -> bf16 channel-pair-interleaved: x2[(b*128+cp)*4096 + a] = {c=2cp, c=2cp+1}
__global__ void prep_x2(const float* __restrict__ x, uint* __restrict__ x2) {
    int idx = blockIdx.x * 256 + threadIdx.x;      // 2,097,152
    int a  = idx & 4095;
    int cp = (idx >> 12) & 127;
    int b  = idx >> 19;
    const float* p = x + ((size_t)(b * 256 + 2 * cp)) * HW + a;
    x2[idx] = pack2(p[0], p[HW]);
}

// ---- w_def -> Bt[o*2304 + tap*256 + c]
__global__ void prep_bt(const float* __restrict__ w_def, ushort* __restrict__ bt) {
    int idx = blockIdx.x * 256 + threadIdx.x;      // 589,824
    int c   = idx & 255;
    int tap = (idx >> 8) % 9;
    int o   = idx / KD;
    __hip_bfloat16 h = __float2bfloat16(w_def[(o * 256 + c) * 9 + tap]);
    bt[idx] = *(ushort*)&h;
}

// ---- w_off -> Bt0[j*2304 + tap*256 + c], rows 18..31 zero
__global__ void prep_bt0(const float* __restrict__ w_off, ushort* __restrict__ bt0) {
    int idx = blockIdx.x * 256 + threadIdx.x;      // 73,728
    int c   = idx & 255;
    int tap = (idx >> 8) % 9;
    int j   = idx / KD;
    float v = (j < 18) ? w_off[(j * 256 + c) * 9 + tap] : 0.f;
    __hip_bfloat16 h = __float2bfloat16(v);
    bt0[idx] = *(ushort*)&h;
}

// ---- fused offset conv: direct implicit GEMM from x2, no im2col ----
// 512 threads (8 waves): wave wv -> (M-quadrant mq = wv&3, N-half nn = wv>>2).
__global__ __launch_bounds__(512) void gemm_off(const uint* __restrict__ x2,
                                                const ushort* __restrict__ bt0,
                                                const float* __restrict__ b_off,
                                                float* __restrict__ off) {
    int id = blockIdx.x;
    int xcd = id & 7;
    int b = xcd >> 1, h = (xcd & 1) * 32 + (id >> 3);
    int t = threadIdx.x, wv = t >> 6, lane = t & 63;
    int mrow = lane & 15, quad = lane >> 4;
    int mq = wv & 3, nn = wv >> 2;

    __shared__ uint   lX[3 * 32 * 64];     // [dy][cp][w] dwords, 24 KB
    __shared__ ushort lB[32 * 576];        // [o][72 chunks of 8, XOR-swizzled], 36 KB

    f32x4 acc = {0.f, 0.f, 0.f, 0.f};

    for (int cb = 0; cb < 4; ++cb) {
#pragma unroll
        for (int s = 0; s < 3; ++s) {      // 24 lX phases over 8 waves
            int q  = s * 8 + wv;
            int dy = q >> 3;
            int y  = h + dy - 1;
            int dl = (q & 7) * 256 + lane * 4;
            int cp = dl >> 6, w4 = dl & 63;
            uint* dst = &lX[q * 256 + lane * 4];
            if ((unsigned)y < 64u) {
                const uint* src = x2 + ((size_t)(b * 128 + cb * 32 + cp)) * HW + y * 64 + w4;
                load_lds16(src, &lX[q * 256]);
            } else {
                uint4 z = {0u, 0u, 0u, 0u};
                *(uint4*)dst = z;
            }
        }
#pragma unroll
        for (int s = 0; s < 5; ++s) {      // 36 lB phases over 8 waves (guarded, wave-uniform)
            int q = s * 8 + wv;
            if (q < 36) {
                int e = q * 512 + lane * 8;
                int o  = e / 576;
                int r  = e - o * 576;
                int chp = r >> 3;
                int ch  = chp ^ (o & 7);
                int tap = ch >> 3, k8 = ch & 7;
                const ushort* src = bt0 + (size_t)o * KD + tap * 256 + cb * 64 + k8 * 8;
                load_lds16(src, &lB[q * 512]);
            }
        }
        __syncthreads();

#pragma unroll
        for (int tap = 0; tap < 9; ++tap) {
            int dy = tap / 3, dx = tap % 3;
            int xx = mq * 16 + mrow + dx - 1;
            bool vx = (unsigned)xx < 64u;
#pragma unroll
            for (int kb = 0; kb < 2; ++kb) {
                int cp0 = kb * 16 + quad * 4;
                uint ad[4];
#pragma unroll
                for (int i = 0; i < 4; ++i)
                    ad[i] = vx ? lX[(dy * 32 + cp0 + i) * 64 + xx] : 0u;
                bf16x8 af = *(bf16x8*)ad;
                int o = nn * 16 + mrow;
                int chs = (tap * 8 + (((kb * 4 + quad)) ^ (o & 7)));
                bf16x8 bfr = *(const bf16x8*)&lB[o * 576 + chs * 8];
                acc = __builtin_amdgcn_mfma_f32_16x16x32_bf16(af, bfr, acc, 0, 0, 0);
            }
        }
        __syncthreads();
    }
    {
        int o = nn * 16 + mrow;
        float bias = (o < 18) ? b_off[o] : 0.f;
        f32x4 v = acc;
        v.x += bias; v.y += bias; v.z += bias; v.w += bias;
        int wpos = mq * 16 + quad * 4;
        *(f32x4*)(off + ((size_t)(b * 32 + o)) * HW + h * 64 + wpos) = v;
    }
}

// ---- fused gather + main GEMM + BN-stats, producer/consumer wave split ----
// 1024 threads: waves 0..7 = producers (gather+interp+stage, the old 512-thread
// staging code verbatim), waves 8..15 = consumers (MFMA + epilogue).
// Round-robin wave->SIMD gives each SIMD 2 producers + 2 consumers, so producer
// vmcnt stalls are covered by consumer MFMA issue.
__global__ __launch_bounds__(1024, 4) void fused_main(const uint* __restrict__ x2,
                                                      const ushort* __restrict__ bt,
                                                      const float* __restrict__ off,
                                                      float* __restrict__ out,
                                                      float* __restrict__ stats) {
    int id = blockIdx.x;                      // 256 blocks
    int xcd = id & 7;
    int b = xcd >> 1, h = (xcd & 1) * 32 + (id >> 3);
    int t = threadIdx.x;
    int wv = t >> 6, lane = t & 63;
    int mrow = lane & 15, quad = lane >> 4;
    bool producer = (wv < 8);
    int w  = t & 63;                          // pos within tile (producer role)
    int cq = (t >> 6) & 7;                    // channel-chunk (producer role)

    __shared__ int    sAc[4][9][64];          // corner plane offsets, 9 KB
    __shared__ float  sWc[4][9][64];          // corner weights, 9 KB
    __shared__ ushort lA[2][64 * 64];         // 2 x 8 KB
    __shared__ ushort lB[2][256 * 64];        // 2 x 32 KB

    // ---- per-tile coords for all 9 taps ----
    for (int i = t; i < 576; i += 1024) {
        int tap = i >> 6, ww = i & 63;
        int hw = h * 64 + ww;
        float oy = off[((size_t)(b * 32 + 2 * tap)) * HW + hw];
        float ox = off[((size_t)(b * 32 + 2 * tap + 1)) * HW + hw];
        float py = oy + (float)(tap / 3 + h - 1);
        float px = ox + (float)(tap % 3 + ww - 1);
        float y0f = floorf(py), x0f = floorf(px);
        float wy1 = py - y0f, wx1 = px - x0f;
        float wy0 = 1.f - wy1, wx0 = 1.f - wx1;
        bool vy0 = (y0f >= 0.f) && (y0f <= 63.f);
        bool vy1 = (y0f >= -1.f) && (y0f <= 62.f);
        bool vx0 = (x0f >= 0.f) && (x0f <= 63.f);
        bool vx1 = (x0f >= -1.f) && (x0f <= 62.f);
        int iy0 = min(max((int)y0f, 0), 63),  iy1 = min(max((int)y0f + 1, 0), 63);
        int ix0 = min(max((int)x0f, 0), 63),  ix1 = min(max((int)x0f + 1, 0), 63);
        sAc[0][tap][ww] = iy0 * 64 + ix0;
        sAc[1][tap][ww] = iy0 * 64 + ix1;
        sAc[2][tap][ww] = iy1 * 64 + ix0;
        sAc[3][tap][ww] = iy1 * 64 + ix1;
        sWc[0][tap][ww] = wy0 * wx0 * (float)(vy0 && vx0);
        sWc[1][tap][ww] = wy0 * wx1 * (float)(vy0 && vx1);
        sWc[2][tap][ww] = wy1 * wx0 * (float)(vy1 && vx0);
        sWc[3][tap][ww] = wy1 * wx1 * (float)(vy1 && vx1);
    }
    __syncthreads();

    f32x4 acc[4][2];
#pragma unroll
    for (int m = 0; m < 4; ++m)
#pragma unroll
        for (int n = 0; n < 2; ++n) acc[m][n] = {0.f, 0.f, 0.f, 0.f};

    const uint* xb = x2 + (size_t)(b * 128) * HW;

    // producer: stage slice sl (tap = sl>>2, cb = sl&3) into (lAb, lBb).
    // Order: issue gather loads -> issue B global_load_lds -> interp -> lA write,
    // so the B staging doesn't sit behind the gather vmcnt wait.
    auto stage = [&](int sl, ushort* lAb, ushort* lBb) {
        int tap = sl >> 2, cb = sl & 3;
        int a0 = sAc[0][tap][w], a1 = sAc[1][tap][w], a2 = sAc[2][tap][w], a3 = sAc[3][tap][w];
        float f0 = sWc[0][tap][w], f1 = sWc[1][tap][w], f2 = sWc[2][tap][w], f3 = sWc[3][tap][w];
        const uint* xp = xb + (size_t)(cb * 32 + cq * 4) * HW;
        uint u0[4], u1[4], u2[4], u3[4];
#pragma unroll
        for (int j = 0; j < 4; ++j) {
            const uint* pq = xp + (size_t)j * HW;
            u0[j] = pq[a0]; u1[j] = pq[a1]; u2[j] = pq[a2]; u3[j] = pq[a3];
        }
#pragma unroll
        for (int s2 = 0; s2 < 4; ++s2) {
            int e = s2 * 512 + t;                  // producers are exactly t in 0..511
            int o = e >> 3, pp = e & 7;
            int k8 = pp ^ (o & 7);
            const ushort* src = bt + (size_t)o * KD + tap * 256 + cb * 64 + k8 * 8;
            load_lds16(src, &lBb[(e & ~63) * 8]);
        }
        uint r[4];
#pragma unroll
        for (int j = 0; j < 4; ++j) {
            float ev = f0 * blo(u0[j]) + f1 * blo(u1[j]) + f2 * blo(u2[j]) + f3 * blo(u3[j]);
            float ov = f0 * bhi(u0[j]) + f1 * bhi(u1[j]) + f2 * bhi(u2[j]) + f3 * bhi(u3[j]);
            r[j] = pack2(ev, ov);
        }
        uint4 g = {r[0], r[1], r[2], r[3]};
        *(uint4*)&lAb[w * 64 + ((cq ^ (w & 7)) * 8)] = g;
    };

    // ---- prologue: producers stage slice 0 into buf 0 ----
    if (producer) stage(0, lA[0], lB[0]);

    int p = 0;
    for (int s = 0; s < 36; ++s) {
        __syncthreads();                       // slice s staged & visible in buf p
        if (producer) {
            if (s + 1 < 36) stage(s + 1, lA[p ^ 1], lB[p ^ 1]);
        } else {
            int wvc = wv - 8;
#pragma unroll
            for (int kb = 0; kb < 2; ++kb) {
                bf16x8 af[4];
#pragma unroll
                for (int m = 0; m < 4; ++m) {
                    int r = m * 16 + mrow;
                    af[m] = *(const bf16x8*)&lA[p][r * 64 + (((kb * 4 + quad) ^ (r & 7)) * 8)];
                }
#pragma unroll
                for (int n = 0; n < 2; ++n) {
                    int r = wvc * 32 + n * 16 + mrow;
                    bf16x8 bfr = *(const bf16x8*)&lB[p][r * 64 + (((kb * 4 + quad) ^ (r & 7)) * 8)];
#pragma unroll
                    for (int m = 0; m < 4; ++m)
                        acc[m][n] = __builtin_amdgcn_mfma_f32_16x16x32_bf16(af[m], bfr, acc[m][n], 0, 0, 0);
                }
            }
        }
        p ^= 1;
    }

    // ---- epilogue (consumers only): store + BN stats ----
    if (!producer) {
        int wvc = wv - 8;
#pragma unroll
        for (int n = 0; n < 2; ++n) {
            int o = wvc * 32 + n * 16 + mrow;
            float ss = 0.f, qq = 0.f;
#pragma unroll
            for (int m = 0; m < 4; ++m) {
                int pos = m * 16 + quad * 4;
                f32x4 v = acc[m][n];
                *(f32x4*)(out + ((size_t)(b * 256 + o)) * HW + h * 64 + pos) = v;
                ss += v.x + v.y + v.z + v.w;
                qq += v.x * v.x + v.y * v.y + v.z * v.z + v.w * v.w;
            }
            ss += __shfl_xor(ss, 16); ss += __shfl_xor(ss, 32);
            qq += __shfl_xor(qq, 16); qq += __shfl_xor(qq, 32);
            if (quad == 0) {
                atomicAdd(&stats[o], ss);
                atomicAdd(&stats[512 + o], qq);
            }
        }
    }
}

// ---- BN finalize + apply ----
__global__ void bn_finalize(const float* __restrict__ stats,
                            const float* __restrict__ gamma,
                            float* __restrict__ ms) {
    int o = threadIdx.x;                      // 256
    float S = stats[o], S2 = stats[512 + o];
    float m  = S / 16384.f;
    float var = S2 / 16384.f - m * m;
    ms[o]       = m;
    ms[256 + o] = gamma[o] * rsqrtf(var + 1e-5f);
}

__global__ void bn_apply(float* __restrict__ out,
                         const float* __restrict__ ms,
                         const float* __restrict__ beta) {
    int idx4 = blockIdx.x * 256 + threadIdx.x;   // 1,048,576 float4s
    int o = (idx4 >> 10) & 255;
    float4 v = ((const float4*)out)[idx4];
    float mu = ms[o], sc = ms[256 + o], be = beta[o];
    v.x = fmaxf((v.x - mu) * sc + be, 0.f);
    v.y = fmaxf((v.y - mu) * sc + be, 0.f);
    v.z = fmaxf((v.z - mu) * sc + be, 0.f);
    v.w = fmaxf((v.w - mu) * sc + be, 0.f);
    ((float4*)out)[idx4] = v;
}

extern "C" void kernel_launch(void* const* d_in, const int* in_sizes, int n_in,
                              void* d_out, int out_size, void* d_ws, size_t ws_size,
                              hipStream_t stream) {
    const float* x     = (const float*)d_in[0];
    const float* w_off = (const float*)d_in[1];
    const float* b_off = (const float*)d_in[2];
    const float* w_def = (const float*)d_in[3];
    const float* gamma = (const float*)d_in[4];
    const float* beta  = (const float*)d_in[5];
    float* out = (float*)d_out;

    char* ws = (char*)d_ws;
    uint*   x2    = (uint*)ws;                          // 8,388,608 B
    ushort* bt    = (ushort*)(ws + 8388608);            // 1,179,648 B
    ushort* bt0   = (ushort*)(ws + 9568256);            // 147,456 B
    float*  off   = (float*)(ws + 9715712);             // 2,097,152 B
    float*  stats = (float*)(ws + 11812864);            // 4,096 B
    float*  ms    = (float*)(ws + 11816960);            // 2,048 B

    hipMemsetAsync(stats, 0, 4096, stream);
    prep_x2 <<<8192, 256, 0, stream>>>(x, x2);
    prep_bt <<<2304, 256, 0, stream>>>(w_def, bt);
    prep_bt0<<<288,  256, 0, stream>>>(w_off, bt0);
    gemm_off<<<256, 512, 0, stream>>>(x2, bt0, b_off, off);
    fused_main<<<256, 1024, 0, stream>>>(x2, bt, off, out, stats);
    bn_finalize<<<1, 256, 0, stream>>>(stats, gamma, ms);
    bn_apply<<<4096, 256, 0, stream>>>(out, ms, beta);
}

// Round 3
// 165.944 us; speedup vs baseline: 1.0840x; 1.0840x over previous
//
#include <hip/hip_runtime.h>
#include <hip/hip_bf16.h>

typedef unsigned int  uint;
typedef unsigned short ushort;
typedef short bf16x8 __attribute__((ext_vector_type(8)));
typedef float f32x4  __attribute__((ext_vector_type(4)));

#define HW   4096
#define KD   2304   // 9 taps * 256 c

__device__ __forceinline__ void load_lds16(const void* g, void* l) {
    __builtin_amdgcn_global_load_lds((const __attribute__((address_space(1))) void*)g,
                                     (__attribute__((address_space(3))) void*)l, 16, 0, 0);
}
__device__ __forceinline__ float blo(uint u) { return __uint_as_float(u << 16); }
__device__ __forceinline__ float bhi(uint u) { return __uint_as_float(u & 0xffff0000u); }
__device__ __forceinline__ uint pack2(float e, float o) {
    __hip_bfloat16 he = __float2bfloat16(e), ho = __float2bfloat16(o);
    return (uint)(*(ushort*)&he) | ((uint)(*(ushort*)&ho) << 16);
}

// ---- x -> bf16 position-major: x2t[(b*4096 + a)*128 + cp] = {c=2cp, c=2cp+1}
// One bilinear corner's 4 channel-pairs (8 channels) become a single 16B load.
__global__ void prep_x2t(const float* __restrict__ x, uint* __restrict__ x2t) {
    __shared__ uint tl[32][65];
    int bidx = blockIdx.x;              // 4 b * 4 cpb * 64 ab = 1024
    int ab  = bidx & 63;
    int cpb = (bidx >> 6) & 3;
    int b   = bidx >> 8;
    int t = threadIdx.x;                // 256
#pragma unroll
    for (int i = 0; i < 8; ++i) {
        int idx = i * 256 + t;
        int cp = idx >> 6, a = idx & 63;           // cp in [0,32)
        const float* p = x + ((size_t)(b * 256 + (cpb * 32 + cp) * 2)) * HW + ab * 64 + a;
        tl[cp][a] = pack2(p[0], p[HW]);
    }
    __syncthreads();
#pragma unroll
    for (int i = 0; i < 8; ++i) {
        int idx = i * 256 + t;
        int a = idx >> 5, cp = idx & 31;
        x2t[((size_t)b * 4096 + ab * 64 + a) * 128 + cpb * 32 + cp] = tl[cp][a];
    }
}

// ---- w_def -> Bt[o*2304 + tap*256 + c]
__global__ void prep_bt(const float* __restrict__ w_def, ushort* __restrict__ bt) {
    int idx = blockIdx.x * 256 + threadIdx.x;      // 589,824
    int c   = idx & 255;
    int tap = (idx >> 8) % 9;
    int o   = idx / KD;
    __hip_bfloat16 h = __float2bfloat16(w_def[(o * 256 + c) * 9 + tap]);
    bt[idx] = *(ushort*)&h;
}

// ---- w_off -> Bt0[j*2304 + tap*256 + c], rows 18..31 zero
__global__ void prep_bt0(const float* __restrict__ w_off, ushort* __restrict__ bt0) {
    int idx = blockIdx.x * 256 + threadIdx.x;      // 73,728
    int c   = idx & 255;
    int tap = (idx >> 8) % 9;
    int j   = idx / KD;
    float v = (j < 18) ? w_off[(j * 256 + c) * 9 + tap] : 0.f;
    __hip_bfloat16 h = __float2bfloat16(v);
    bt0[idx] = *(ushort*)&h;
}

// ---- fused offset conv: direct implicit GEMM from x2t ----
// 512 threads (8 waves): wave wv -> (M-quadrant mq = wv&3, N-half nn = wv>>2).
// A-tile staged as lX[dy][w][cp'] with cp' = cp ^ ((w&7)*4) XOR-swizzle,
// applied on the global SOURCE address (global_load_lds dst stays linear).
__global__ __launch_bounds__(512) void gemm_off(const uint* __restrict__ x2t,
                                                const ushort* __restrict__ bt0,
                                                const float* __restrict__ b_off,
                                                float* __restrict__ off) {
    int id = blockIdx.x;
    int xcd = id & 7;
    int b = xcd >> 1, h = (xcd & 1) * 32 + (id >> 3);
    int t = threadIdx.x, wv = t >> 6, lane = t & 63;
    int mrow = lane & 15, quad = lane >> 4;
    int mq = wv & 3, nn = wv >> 2;

    __shared__ uint   lX[3 * 64 * 32];     // [dy][w][cp'] dwords, 24 KB
    __shared__ ushort lB[32 * 576];        // [o][72 chunks of 8, XOR-swizzled], 36 KB

    f32x4 acc = {0.f, 0.f, 0.f, 0.f};

    for (int cb = 0; cb < 4; ++cb) {
#pragma unroll
        for (int s = 0; s < 3; ++s) {      // 24 lX phases over 8 waves
            int q   = s * 8 + wv;
            int dy  = q >> 3;              // wave-uniform
            int y   = h + dy - 1;
            int sub = q & 7;
            int wl  = sub * 8 + (lane >> 3);
            int cps = ((lane & 7) ^ ((lane >> 3) & 7)) * 4;   // pre-swizzled source cp
            if ((unsigned)y < 64u) {
                const uint* src = x2t + ((size_t)(b * 4096 + y * 64 + wl)) * 128 + cb * 32 + cps;
                load_lds16(src, &lX[q * 256]);
            } else {
                uint4 z = {0u, 0u, 0u, 0u};
                *(uint4*)&lX[q * 256 + lane * 4] = z;
            }
        }
#pragma unroll
        for (int s = 0; s < 5; ++s) {      // 36 lB phases over 8 waves (guarded, wave-uniform)
            int q = s * 8 + wv;
            if (q < 36) {
                int e = q * 512 + lane * 8;
                int o  = e / 576;
                int r  = e - o * 576;
                int chp = r >> 3;
                int ch  = chp ^ (o & 7);
                int tap = ch >> 3, k8 = ch & 7;
                const ushort* src = bt0 + (size_t)o * KD + tap * 256 + cb * 64 + k8 * 8;
                load_lds16(src, &lB[q * 512]);
            }
        }
        __syncthreads();

#pragma unroll
        for (int tap = 0; tap < 9; ++tap) {
            int dy = tap / 3, dx = tap % 3;
            int xx = mq * 16 + mrow + dx - 1;
            bool vx = (unsigned)xx < 64u;
            int xc = min(max(xx, 0), 63);
#pragma unroll
            for (int kb = 0; kb < 2; ++kb) {
                int cp0 = kb * 16 + quad * 4;
                uint4 ad = {0u, 0u, 0u, 0u};
                if (vx) ad = *(const uint4*)&lX[dy * 2048 + xc * 32 + (cp0 ^ ((xc & 7) * 4))];
                bf16x8 af = *(bf16x8*)&ad;
                int o = nn * 16 + mrow;
                int chs = (tap * 8 + (((kb * 4 + quad)) ^ (o & 7)));
                bf16x8 bfr = *(const bf16x8*)&lB[o * 576 + chs * 8];
                acc = __builtin_amdgcn_mfma_f32_16x16x32_bf16(af, bfr, acc, 0, 0, 0);
            }
        }
        __syncthreads();
    }
    {
        int o = nn * 16 + mrow;
        float bias = (o < 18) ? b_off[o] : 0.f;
        f32x4 v = acc;
        v.x += bias; v.y += bias; v.z += bias; v.w += bias;
        int wpos = mq * 16 + quad * 4;
        *(f32x4*)(off + ((size_t)(b * 32 + o)) * HW + h * 64 + wpos) = v;
    }
}

// ---- fused gather + main GEMM + BN-stats, producer/consumer wave split ----
// 1024 threads: waves 0..7 = producers (gather+interp+stage), waves 8..15 =
// consumers (MFMA + epilogue). Gather reads position-major x2t: one
// dwordx4 per bilinear corner (4 VMEM instrs/thread/slice instead of 16).
__global__ __launch_bounds__(1024, 4) void fused_main(const uint* __restrict__ x2t,
                                                      const ushort* __restrict__ bt,
                                                      const float* __restrict__ off,
                                                      float* __restrict__ out,
                                                      float* __restrict__ stats) {
    int id = blockIdx.x;                      // 256 blocks
    int xcd = id & 7;
    int b = xcd >> 1, h = (xcd & 1) * 32 + (id >> 3);
    int t = threadIdx.x;
    int wv = t >> 6, lane = t & 63;
    int mrow = lane & 15, quad = lane >> 4;
    bool producer = (wv < 8);
    int w  = t & 63;                          // pos within tile (producer role)
    int cq = (t >> 6) & 7;                    // channel-chunk (producer role)

    __shared__ int    sAc[4][9][64];          // corner plane offsets, 9 KB
    __shared__ float  sWc[4][9][64];          // corner weights, 9 KB
    __shared__ ushort lA[2][64 * 64];         // 2 x 8 KB
    __shared__ ushort lB[2][256 * 64];        // 2 x 32 KB

    // ---- per-tile coords for all 9 taps ----
    for (int i = t; i < 576; i += 1024) {
        int tap = i >> 6, ww = i & 63;
        int hw = h * 64 + ww;
        float oy = off[((size_t)(b * 32 + 2 * tap)) * HW + hw];
        float ox = off[((size_t)(b * 32 + 2 * tap + 1)) * HW + hw];
        float py = oy + (float)(tap / 3 + h - 1);
        float px = ox + (float)(tap % 3 + ww - 1);
        float y0f = floorf(py), x0f = floorf(px);
        float wy1 = py - y0f, wx1 = px - x0f;
        float wy0 = 1.f - wy1, wx0 = 1.f - wx1;
        bool vy0 = (y0f >= 0.f) && (y0f <= 63.f);
        bool vy1 = (y0f >= -1.f) && (y0f <= 62.f);
        bool vx0 = (x0f >= 0.f) && (x0f <= 63.f);
        bool vx1 = (x0f >= -1.f) && (x0f <= 62.f);
        int iy0 = min(max((int)y0f, 0), 63),  iy1 = min(max((int)y0f + 1, 0), 63);
        int ix0 = min(max((int)x0f, 0), 63),  ix1 = min(max((int)x0f + 1, 0), 63);
        sAc[0][tap][ww] = iy0 * 64 + ix0;
        sAc[1][tap][ww] = iy0 * 64 + ix1;
        sAc[2][tap][ww] = iy1 * 64 + ix0;
        sAc[3][tap][ww] = iy1 * 64 + ix1;
        sWc[0][tap][ww] = wy0 * wx0 * (float)(vy0 && vx0);
        sWc[1][tap][ww] = wy0 * wx1 * (float)(vy0 && vx1);
        sWc[2][tap][ww] = wy1 * wx0 * (float)(vy1 && vx0);
        sWc[3][tap][ww] = wy1 * wx1 * (float)(vy1 && vx1);
    }
    __syncthreads();

    f32x4 acc[4][2];
#pragma unroll
    for (int m = 0; m < 4; ++m)
#pragma unroll
        for (int n = 0; n < 2; ++n) acc[m][n] = {0.f, 0.f, 0.f, 0.f};

    const uint* xb = x2t + (size_t)b * 4096 * 128;

    // producer: stage slice sl (tap = sl>>2, cb = sl&3) into (lAb, lBb).
    // Gather: one dwordx4 per corner (4 channel-pairs, contiguous in x2t).
    // Order: issue gathers -> issue B global_load_lds -> interp -> lA write.
    auto stage = [&](int sl, ushort* lAb, ushort* lBb) {
        int tap = sl >> 2, cb = sl & 3;
        int a0 = sAc[0][tap][w], a1 = sAc[1][tap][w], a2 = sAc[2][tap][w], a3 = sAc[3][tap][w];
        float f0 = sWc[0][tap][w], f1 = sWc[1][tap][w], f2 = sWc[2][tap][w], f3 = sWc[3][tap][w];
        const uint* xp = xb + cb * 32 + cq * 4;
        uint4 v0 = *(const uint4*)(xp + (size_t)a0 * 128);
        uint4 v1 = *(const uint4*)(xp + (size_t)a1 * 128);
        uint4 v2 = *(const uint4*)(xp + (size_t)a2 * 128);
        uint4 v3 = *(const uint4*)(xp + (size_t)a3 * 128);
#pragma unroll
        for (int s2 = 0; s2 < 4; ++s2) {
            int e = s2 * 512 + t;                  // producers are exactly t in 0..511
            int o = e >> 3, pp = e & 7;
            int k8 = pp ^ (o & 7);
            const ushort* src = bt + (size_t)o * KD + tap * 256 + cb * 64 + k8 * 8;
            load_lds16(src, &lBb[(e & ~63) * 8]);
        }
        const uint* c0 = (const uint*)&v0;
        const uint* c1 = (const uint*)&v1;
        const uint* c2 = (const uint*)&v2;
        const uint* c3 = (const uint*)&v3;
        uint r[4];
#pragma unroll
        for (int j = 0; j < 4; ++j) {
            float ev = f0 * blo(c0[j]) + f1 * blo(c1[j]) + f2 * blo(c2[j]) + f3 * blo(c3[j]);
            float ov = f0 * bhi(c0[j]) + f1 * bhi(c1[j]) + f2 * bhi(c2[j]) + f3 * bhi(c3[j]);
            r[j] = pack2(ev, ov);
        }
        uint4 g = {r[0], r[1], r[2], r[3]};
        *(uint4*)&lAb[w * 64 + ((cq ^ (w & 7)) * 8)] = g;
    };

    // ---- prologue: producers stage slice 0 into buf 0 ----
    if (producer) stage(0, lA[0], lB[0]);

    int p = 0;
    for (int s = 0; s < 36; ++s) {
        __syncthreads();                       // slice s staged & visible in buf p
        if (producer) {
            if (s + 1 < 36) stage(s + 1, lA[p ^ 1], lB[p ^ 1]);
        } else {
            int wvc = wv - 8;
#pragma unroll
            for (int kb = 0; kb < 2; ++kb) {
                bf16x8 af[4];
#pragma unroll
                for (int m = 0; m < 4; ++m) {
                    int r = m * 16 + mrow;
                    af[m] = *(const bf16x8*)&lA[p][r * 64 + (((kb * 4 + quad) ^ (r & 7)) * 8)];
                }
#pragma unroll
                for (int n = 0; n < 2; ++n) {
                    int r = wvc * 32 + n * 16 + mrow;
                    bf16x8 bfr = *(const bf16x8*)&lB[p][r * 64 + (((kb * 4 + quad) ^ (r & 7)) * 8)];
#pragma unroll
                    for (int m = 0; m < 4; ++m)
                        acc[m][n] = __builtin_amdgcn_mfma_f32_16x16x32_bf16(af[m], bfr, acc[m][n], 0, 0, 0);
                }
            }
        }
        p ^= 1;
    }

    // ---- epilogue (consumers only): store + BN stats ----
    if (!producer) {
        int wvc = wv - 8;
#pragma unroll
        for (int n = 0; n < 2; ++n) {
            int o = wvc * 32 + n * 16 + mrow;
            float ss = 0.f, qq = 0.f;
#pragma unroll
            for (int m = 0; m < 4; ++m) {
                int pos = m * 16 + quad * 4;
                f32x4 v = acc[m][n];
                *(f32x4*)(out + ((size_t)(b * 256 + o)) * HW + h * 64 + pos) = v;
                ss += v.x + v.y + v.z + v.w;
                qq += v.x * v.x + v.y * v.y + v.z * v.z + v.w * v.w;
            }
            ss += __shfl_xor(ss, 16); ss += __shfl_xor(ss, 32);
            qq += __shfl_xor(qq, 16); qq += __shfl_xor(qq, 32);
            if (quad == 0) {
                atomicAdd(&stats[o], ss);
                atomicAdd(&stats[512 + o], qq);
            }
        }
    }
}

// ---- BN finalize + apply ----
__global__ void bn_finalize(const float* __restrict__ stats,
                            const float* __restrict__ gamma,
                            float* __restrict__ ms) {
    int o = threadIdx.x;                      // 256
    float S = stats[o], S2 = stats[512 + o];
    float m  = S / 16384.f;
    float var = S2 / 16384.f - m * m;
    ms[o]       = m;
    ms[256 + o] = gamma[o] * rsqrtf(var + 1e-5f);
}

__global__ void bn_apply(float* __restrict__ out,
                         const float* __restrict__ ms,
                         const float* __restrict__ beta) {
    int idx4 = blockIdx.x * 256 + threadIdx.x;   // 1,048,576 float4s
    int o = (idx4 >> 10) & 255;
    float4 v = ((const float4*)out)[idx4];
    float mu = ms[o], sc = ms[256 + o], be = beta[o];
    v.x = fmaxf((v.x - mu) * sc + be, 0.f);
    v.y = fmaxf((v.y - mu) * sc + be, 0.f);
    v.z = fmaxf((v.z - mu) * sc + be, 0.f);
    v.w = fmaxf((v.w - mu) * sc + be, 0.f);
    ((float4*)out)[idx4] = v;
}

extern "C" void kernel_launch(void* const* d_in, const int* in_sizes, int n_in,
                              void* d_out, int out_size, void* d_ws, size_t ws_size,
                              hipStream_t stream) {
    const float* x     = (const float*)d_in[0];
    const float* w_off = (const float*)d_in[1];
    const float* b_off = (const float*)d_in[2];
    const float* w_def = (const float*)d_in[3];
    const float* gamma = (const float*)d_in[4];
    const float* beta  = (const float*)d_in[5];
    float* out = (float*)d_out;

    char* ws = (char*)d_ws;
    uint*   x2t   = (uint*)ws;                          // 8,388,608 B
    ushort* bt    = (ushort*)(ws + 8388608);            // 1,179,648 B
    ushort* bt0   = (ushort*)(ws + 9568256);            // 147,456 B
    float*  off   = (float*)(ws + 9715712);             // 2,097,152 B
    float*  stats = (float*)(ws + 11812864);            // 4,096 B
    float*  ms    = (float*)(ws + 11816960);            // 2,048 B

    hipMemsetAsync(stats, 0, 4096, stream);
    prep_x2t<<<1024, 256, 0, stream>>>(x, x2t);
    prep_bt <<<2304, 256, 0, stream>>>(w_def, bt);
    prep_bt0<<<288,  256, 0, stream>>>(w_off, bt0);
    gemm_off<<<256, 512, 0, stream>>>(x2t, bt0, b_off, off);
    fused_main<<<256, 1024, 0, stream>>>(x2t, bt, off, out, stats);
    bn_finalize<<<1, 256, 0, stream>>>(stats, gamma, ms);
    bn_apply<<<4096, 256, 0, stream>>>(out, ms, beta);
}